// Round 1
// baseline (6352.667 us; speedup 1.0000x reference)
//
#include <hip/hip_runtime.h>
#include <hip/hip_bf16.h>
#include <math.h>

// ---------------------------------------------------------------------------
// 2-layer tanh RNN, B=64 S=512 I=256 H=512, fp32 in/out, bf16 MFMA compute.
//
// ws layout (bytes):
//   [0)        Wp_hh0  bf16 packed  512 KB
//   [512K)     Wp_hh1  bf16 packed  512 KB
//   [1M)       Wp_ih1  bf16 packed  512 KB
//   [1.5M)     Wp_ih0  bf16 packed  256 KB
//   [2M)       xb      bf16 [32768][256]    16 MB
//   [18874368) out0b   bf16 [512][64][512]  32 MB   (rows t*64+b)
//   [52428800) pre     fp32 [512][64][512]  64 MB   (shared by pre0/pre1)
//   total 119537664 B (~114 MB)
// ---------------------------------------------------------------------------

typedef __attribute__((ext_vector_type(8))) short  short8;
typedef __attribute__((ext_vector_type(4))) float  floatx4;

#define MFMA_BF16(a, b, c) __builtin_amdgcn_mfma_f32_16x16x32_bf16((a), (b), (c), 0, 0, 0)

// offsets in u16 units for bf16 regions
#define OFS_HH0   ((size_t)0)
#define OFS_HH1   ((size_t)262144)
#define OFS_IH1   ((size_t)524288)
#define OFS_IH0   ((size_t)786432)
#define OFS_XB    ((size_t)1048576)
#define OFS_OUT0B ((size_t)9437184)
#define PRE_B     ((size_t)52428800)   // byte offset of fp32 pre buffer

__device__ __forceinline__ unsigned short f2bf(float f) {
    unsigned u = __builtin_bit_cast(unsigned, f);
    u += 0x7fffu + ((u >> 16) & 1u);          // round-to-nearest-even
    return (unsigned short)(u >> 16);
}
__device__ __forceinline__ float bf2f(unsigned short h) {
    return __builtin_bit_cast(float, ((unsigned)h) << 16);
}

// ---- prep: pack weights into MFMA B-fragment order + convert x to bf16 ----
// B-frag order for 16x16x32 bf16: for n-tile nt, k-tile kt, lane l holds
// W[16*nt + (l&15)][32*kt + 8*(l>>4) + j], j=0..7, stored contiguously.
__device__ __forceinline__ void pack_w(const float* __restrict__ W,
                                       unsigned short* __restrict__ Wp,
                                       int KT, int idx) {
    int l  = idx & 63;
    int kt = (idx >> 6) % KT;
    int nt = (idx >> 6) / KT;
    int Kdim = KT * 32;
    int row = nt * 16 + (l & 15);
    int col = kt * 32 + (l >> 4) * 8;
    const float* s = W + (size_t)row * Kdim + col;
    short8 v;
#pragma unroll
    for (int j = 0; j < 8; ++j) v[j] = (short)f2bf(s[j]);
    *(short8*)(Wp + (size_t)idx * 8) = v;
}

__global__ void prep_kernel(const float* __restrict__ x,
                            const float* __restrict__ whh0,
                            const float* __restrict__ whh1,
                            const float* __restrict__ wih1,
                            const float* __restrict__ wih0,
                            unsigned short* __restrict__ wsb) {
    int blk = blockIdx.x, tid = threadIdx.x;
    if (blk < 128) {
        pack_w(whh0, wsb + OFS_HH0, 16, blk * 256 + tid);
    } else if (blk < 256) {
        pack_w(whh1, wsb + OFS_HH1, 16, (blk - 128) * 256 + tid);
    } else if (blk < 384) {
        pack_w(wih1, wsb + OFS_IH1, 16, (blk - 256) * 256 + tid);
    } else if (blk < 448) {
        pack_w(wih0, wsb + OFS_IH0, 8, (blk - 384) * 256 + tid);
    } else {
        size_t e = ((size_t)(blk - 448) * 256 + tid) * 8;   // 4096 blocks * 2048 = 8388608
        const float* s = x + e;
        short8 v;
#pragma unroll
        for (int j = 0; j < 8; ++j) v[j] = (short)f2bf(s[j]);
        *(short8*)(wsb + OFS_XB + e) = v;
    }
}

// ---- proj: pre = A(bf16, rows x Kdim) @ W^T + bias1 + bias2 -> fp32 -------
// block = 512 thr (8 waves), covers 64 rows x all 512 cols. grid = 512.
// wave w: mg = w>>1 picks 16-row group, nh = w&1 picks 256-col half.
// remap=1: GEMM row r = b*512+t  ->  out row t*64+b   (layer-0 input proj)
__global__ __launch_bounds__(512) void proj_kernel(
        const unsigned short* __restrict__ A,
        const unsigned short* __restrict__ Wp,
        const float* __restrict__ bias1, const float* __restrict__ bias2,
        float* __restrict__ out, int KT, int remap) {
    int tid = threadIdx.x, blk = blockIdx.x;
    int w = tid >> 6, l = tid & 63, lm = l & 15, lq = l >> 4;
    int mg = w >> 1, nh = w & 1;
    int Kdim = KT * 32;
    int r0 = blk * 64 + mg * 16;

    floatx4 acc[16];
#pragma unroll
    for (int i = 0; i < 16; ++i) acc[i] = (floatx4)0.f;

    for (int kt = 0; kt < KT; ++kt) {
        short8 a = *(const short8*)(A + (size_t)(r0 + lm) * Kdim + kt * 32 + lq * 8);
#pragma unroll
        for (int i = 0; i < 16; ++i) {
            int ntg = nh * 16 + i;
            short8 b = *(const short8*)(Wp + (((size_t)ntg * KT + kt) * 64 + l) * 8);
            acc[i] = MFMA_BF16(a, b, acc[i]);
        }
    }
#pragma unroll
    for (int i = 0; i < 16; ++i) {
        int n = (nh * 16 + i) * 16 + lm;
        float bs = bias1[n] + bias2[n];
#pragma unroll
        for (int r = 0; r < 4; ++r) {
            int row = r0 + lq * 4 + r;
            int orow = remap ? ((row & 511) * 64 + (row >> 9)) : row;
            out[(size_t)orow * 512 + n] = acc[i][r] + bs;
        }
    }
}

// ---- recur: persistent scan, 4 blocks x 16 batches, 512 steps ------------
// h kept in LDS as bf16 (padded rows, 16B-aligned stride 520*2=1040B).
// B-fragments for k-tiles 0..7 register-resident (128 VGPR), 8..15 streamed
// from L2. acc fp32, tanh fp32, h rounded RNE to bf16 per step.
__global__ __launch_bounds__(512) void recur_kernel(
        const float* __restrict__ pre,          // [512][64][512] fp32
        const unsigned short* __restrict__ Wp,  // packed bf16, KT=16
        unsigned short* __restrict__ out0b,     // bf16 [512][64][512] (layer 0)
        const float* __restrict__ wfc, const float* __restrict__ bfc,
        float* __restrict__ out, int dofc) {
    __shared__ unsigned short h_lds[16][520];

    int tid = threadIdx.x;
    int w = tid >> 6, l = tid & 63, lm = l & 15, lq = l >> 4;
    int nt0 = w * 4;                 // this wave's 4 n-tiles -> cols [64w, 64w+64)
    int b0 = blockIdx.x * 16;        // batch group

    for (int i = tid; i < 16 * 520; i += 512) ((unsigned short*)h_lds)[i] = 0;
    __syncthreads();

    // register-resident B fragments, k-tiles 0..7
    short8 breg[4][8];
#pragma unroll
    for (int i = 0; i < 4; ++i)
#pragma unroll
        for (int kt = 0; kt < 8; ++kt)
            breg[i][kt] = *(const short8*)(Wp + (((size_t)(nt0 + i) * 16 + kt) * 64 + l) * 8);

    for (int t = 0; t < 512; ++t) {
        // prefetch pre tile (hidden behind the MFMA loop)
        const float* pb = pre + ((size_t)t * 64 + b0) * 512;
        float pv[4][4];
#pragma unroll
        for (int i = 0; i < 4; ++i) {
            int n = (nt0 + i) * 16 + lm;
#pragma unroll
            for (int r = 0; r < 4; ++r) pv[i][r] = pb[(size_t)(lq * 4 + r) * 512 + n];
        }

        floatx4 acc[4];
#pragma unroll
        for (int i = 0; i < 4; ++i) acc[i] = (floatx4)0.f;

#pragma unroll
        for (int kt = 0; kt < 8; ++kt) {
            short8 a = *(const short8*)&h_lds[lm][kt * 32 + lq * 8];
#pragma unroll
            for (int i = 0; i < 4; ++i) acc[i] = MFMA_BF16(a, breg[i][kt], acc[i]);
        }
#pragma unroll
        for (int kt = 8; kt < 16; ++kt) {
            short8 a = *(const short8*)&h_lds[lm][kt * 32 + lq * 8];
#pragma unroll
            for (int i = 0; i < 4; ++i) {
                short8 b = *(const short8*)(Wp + (((size_t)(nt0 + i) * 16 + kt) * 64 + l) * 8);
                acc[i] = MFMA_BF16(a, b, acc[i]);
            }
        }

        __syncthreads();   // all reads of h_t done
#pragma unroll
        for (int i = 0; i < 4; ++i) {
            int n = (nt0 + i) * 16 + lm;
#pragma unroll
            for (int r = 0; r < 4; ++r) {
                float h = tanhf(acc[i][r] + pv[i][r]);
                h_lds[lq * 4 + r][n] = f2bf(h);
            }
        }
        __syncthreads();   // h_{t+1} visible to all

        if (!dofc) {
            // coalesced bf16 copy of h_{t+1} -> out0b rows t*64+b
            int row = tid >> 5;
            int c = (tid & 31) * 16;
            const floatx4* s = (const floatx4*)&h_lds[row][c];
            floatx4* d = (floatx4*)(out0b + ((size_t)t * 64 + b0 + row) * 512 + c);
            d[0] = s[0];
            d[1] = s[1];
        }
    }

    if (dofc && tid < 160) {   // FC head: 16 batches x 10 classes
        int b = tid / 10, c = tid % 10;
        float s = bfc[c];
        for (int n = 0; n < 512; ++n) s += bf2f(h_lds[b][n]) * wfc[c * 512 + n];
        out[(size_t)(b0 + b) * 10 + c] = s;
    }
}

extern "C" void kernel_launch(void* const* d_in, const int* in_sizes, int n_in,
                              void* d_out, int out_size, void* d_ws, size_t ws_size,
                              hipStream_t stream) {
    const float* x    = (const float*)d_in[0];
    const float* wih0 = (const float*)d_in[1];
    const float* whh0 = (const float*)d_in[2];
    const float* bih0 = (const float*)d_in[3];
    const float* bhh0 = (const float*)d_in[4];
    const float* wih1 = (const float*)d_in[5];
    const float* whh1 = (const float*)d_in[6];
    const float* bih1 = (const float*)d_in[7];
    const float* bhh1 = (const float*)d_in[8];
    const float* wfc  = (const float*)d_in[9];
    const float* bfc  = (const float*)d_in[10];
    float* out = (float*)d_out;

    unsigned short* wsb   = (unsigned short*)d_ws;
    unsigned short* xb    = wsb + OFS_XB;
    unsigned short* out0b = wsb + OFS_OUT0B;
    float* pre = (float*)((char*)d_ws + PRE_B);

    // 1. pack weights (bf16 B-frag order) + convert x to bf16
    prep_kernel<<<dim3(4544), dim3(256), 0, stream>>>(x, whh0, whh1, wih1, wih0, wsb);
    // 2. pre0 = x @ w_ih0^T + b_ih0 + b_hh0   (rows b*512+t -> pre[t][b][:])
    proj_kernel<<<dim3(512), dim3(512), 0, stream>>>(xb, wsb + OFS_IH0, bih0, bhh0, pre, 8, 1);
    // 3. layer-0 scan -> out0b (bf16, rows t*64+b)
    recur_kernel<<<dim3(4), dim3(512), 0, stream>>>(pre, wsb + OFS_HH0, out0b,
                                                    nullptr, nullptr, nullptr, 0);
    // 4. pre1 = out0 @ w_ih1^T + b_ih1 + b_hh1  (rows already t*64+b)
    proj_kernel<<<dim3(512), dim3(512), 0, stream>>>(out0b, wsb + OFS_IH1, bih1, bhh1, pre, 16, 0);
    // 5. layer-1 scan + FC head -> out
    recur_kernel<<<dim3(4), dim3(512), 0, stream>>>(pre, wsb + OFS_HH1, nullptr,
                                                    wfc, bfc, out, 1);
}

// Round 2
// 4580.776 us; speedup vs baseline: 1.3868x; 1.3868x over previous
//
#include <hip/hip_runtime.h>
#include <hip/hip_bf16.h>
#include <math.h>

// ---------------------------------------------------------------------------
// 2-layer tanh RNN, B=64 S=512 I=256 H=512, fp32 in/out, bf16 MFMA compute.
//
// ws layout (bytes):
//   [0)        Wp_hh0  bf16 packed  512 KB
//   [512K)     Wp_hh1  bf16 packed  512 KB
//   [1M)       Wp_ih1  bf16 packed  512 KB
//   [1.5M)     Wp_ih0  bf16 packed  256 KB
//   [2M)       xb      bf16 [32768][256]    16 MB
//   [18874368) out0b   bf16 [512][64][512]  32 MB   (rows t*64+b)
//   [52428800) pre     fp32 PACKED [t][bg][tid][i][r]  64 MB
//   total ~114 MB
// ---------------------------------------------------------------------------

typedef __attribute__((ext_vector_type(8))) short  short8;
typedef __attribute__((ext_vector_type(4))) float  floatx4;

#define MFMA_BF16(a, b, c) __builtin_amdgcn_mfma_f32_16x16x32_bf16((a), (b), (c), 0, 0, 0)

// offsets in u16 units for bf16 regions
#define OFS_HH0   ((size_t)0)
#define OFS_HH1   ((size_t)262144)
#define OFS_IH1   ((size_t)524288)
#define OFS_IH0   ((size_t)786432)
#define OFS_XB    ((size_t)1048576)
#define OFS_OUT0B ((size_t)9437184)
#define PRE_B     ((size_t)52428800)   // byte offset of fp32 pre buffer

__device__ __forceinline__ unsigned short f2bf(float f) {
    unsigned u = __builtin_bit_cast(unsigned, f);
    u += 0x7fffu + ((u >> 16) & 1u);          // round-to-nearest-even
    return (unsigned short)(u >> 16);
}
__device__ __forceinline__ float bf2f(unsigned short h) {
    return __builtin_bit_cast(float, ((unsigned)h) << 16);
}

// fast tanh: ~7 VALU instr, rel err ~1e-6 (vs bf16 rel step 4e-3)
__device__ __forceinline__ float fast_tanh(float x) {
    float z = fminf(9.0f, fmaxf(-9.0f, x));
    float e = __builtin_amdgcn_exp2f(z * 2.88539008f);   // e^{2z}
    return (e - 1.0f) * __builtin_amdgcn_rcpf(e + 1.0f);
}

// ---- prep: pack weights into MFMA B-fragment order + convert x to bf16 ----
__device__ __forceinline__ void pack_w(const float* __restrict__ W,
                                       unsigned short* __restrict__ Wp,
                                       int KT, int idx) {
    int l  = idx & 63;
    int kt = (idx >> 6) % KT;
    int nt = (idx >> 6) / KT;
    int Kdim = KT * 32;
    int row = nt * 16 + (l & 15);
    int col = kt * 32 + (l >> 4) * 8;
    const float* s = W + (size_t)row * Kdim + col;
    short8 v;
#pragma unroll
    for (int j = 0; j < 8; ++j) v[j] = (short)f2bf(s[j]);
    *(short8*)(Wp + (size_t)idx * 8) = v;
}

__global__ void prep_kernel(const float* __restrict__ x,
                            const float* __restrict__ whh0,
                            const float* __restrict__ whh1,
                            const float* __restrict__ wih1,
                            const float* __restrict__ wih0,
                            unsigned short* __restrict__ wsb) {
    int blk = blockIdx.x, tid = threadIdx.x;
    if (blk < 128) {
        pack_w(whh0, wsb + OFS_HH0, 16, blk * 256 + tid);
    } else if (blk < 256) {
        pack_w(whh1, wsb + OFS_HH1, 16, (blk - 128) * 256 + tid);
    } else if (blk < 384) {
        pack_w(wih1, wsb + OFS_IH1, 16, (blk - 256) * 256 + tid);
    } else if (blk < 448) {
        pack_w(wih0, wsb + OFS_IH0, 8, (blk - 384) * 256 + tid);
    } else {
        size_t e = ((size_t)(blk - 448) * 256 + tid) * 8;
        const float* s = x + e;
        short8 v;
#pragma unroll
        for (int j = 0; j < 8; ++j) v[j] = (short)f2bf(s[j]);
        *(short8*)(wsb + OFS_XB + e) = v;
    }
}

// ---- proj: pre = A(bf16) @ W^T + bias1 + bias2 -> fp32, PACKED layout -----
// packed idx = (((t*4 + bg)*512 + tid2)*4 + i2)*4 + r2  (floats), where for
// recur block bg, thread tid2 = w*64+lq*16+lm reads pv[i2][r2] as floatx4[i2].
// remap=1: GEMM row = b*512+t (layer 0); remap=0: row = t*64+b (layer 1).
__global__ __launch_bounds__(512) void proj_kernel(
        const unsigned short* __restrict__ A,
        const unsigned short* __restrict__ Wp,
        const float* __restrict__ bias1, const float* __restrict__ bias2,
        float* __restrict__ out, int KT, int remap) {
    int tid = threadIdx.x, blk = blockIdx.x;
    int w = tid >> 6, l = tid & 63, lm = l & 15, lq = l >> 4;
    int mg = w >> 1, nh = w & 1;
    int Kdim = KT * 32;
    int r0 = blk * 64 + mg * 16;

    floatx4 acc[16];
#pragma unroll
    for (int i = 0; i < 16; ++i) acc[i] = (floatx4)0.f;

    for (int kt = 0; kt < KT; ++kt) {
        short8 a = *(const short8*)(A + (size_t)(r0 + lm) * Kdim + kt * 32 + lq * 8);
#pragma unroll
        for (int i = 0; i < 16; ++i) {
            int ntg = nh * 16 + i;
            short8 b = *(const short8*)(Wp + (((size_t)ntg * KT + kt) * 64 + l) * 8);
            acc[i] = MFMA_BF16(a, b, acc[i]);
        }
    }
#pragma unroll
    for (int i = 0; i < 16; ++i) {
        int n = (nh * 16 + i) * 16 + lm;
        float bs = bias1[n] + bias2[n];
        int w2 = n >> 6, i2 = (n >> 4) & 3, lm2 = n & 15;
#pragma unroll
        for (int r = 0; r < 4; ++r) {
            int row = r0 + lq * 4 + r;
            int tt, b;
            if (remap) { b = row >> 9; tt = row & 511; }
            else       { tt = row >> 6; b = row & 63; }
            int bg = b >> 4, br = b & 15;
            int tid2 = w2 * 64 + (br >> 2) * 16 + lm2;
            size_t idx = ((((size_t)tt * 4 + bg) * 512 + tid2) * 4 + i2) * 4 + (br & 3);
            out[idx] = acc[i][r] + bs;
        }
    }
}

// ---- recur: persistent scan, 4 blocks x 16 batches, 512 steps ------------
// h double-buffered in LDS bf16 (stride 520 u16: conflict-free b128 A-reads).
// B k-tiles 0..11 register-resident (192 VGPR), 12..15 streamed from L2.
// 1 barrier/step. pre read as 4 coalesced dwordx4/thread (packed layout).
__global__ __launch_bounds__(512, 2) void recur_kernel(
        const float* __restrict__ pre,          // packed fp32
        const unsigned short* __restrict__ Wp,  // packed bf16, KT=16
        unsigned short* __restrict__ out0b,     // bf16 [512][64][512] (layer 0)
        const float* __restrict__ wfc, const float* __restrict__ bfc,
        float* __restrict__ out, int dofc) {
    __shared__ unsigned short h_lds[2][16][520];

    int tid = threadIdx.x;
    int w = tid >> 6, l = tid & 63, lm = l & 15, lq = l >> 4;
    int nt0 = w * 4;                 // this wave's 4 n-tiles -> cols [64w, 64w+64)
    int b0 = blockIdx.x * 16;        // batch group

    for (int i = tid; i < 16 * 520; i += 512) ((unsigned short*)&h_lds[0][0][0])[i] = 0;

    // register-resident B fragments, k-tiles 0..11
    short8 breg[4][12];
#pragma unroll
    for (int i = 0; i < 4; ++i)
#pragma unroll
        for (int kt = 0; kt < 12; ++kt)
            breg[i][kt] = *(const short8*)(Wp + (((size_t)(nt0 + i) * 16 + kt) * 64 + l) * 8);

    __syncthreads();

    for (int t = 0; t < 512; ++t) {
        int p = t & 1;

        // coalesced pre load: 4 consecutive float4 per thread (64B)
        const floatx4* pv_ptr =
            (const floatx4*)(pre + (((size_t)t * 4 + blockIdx.x) * 512 + tid) * 16);
        floatx4 pv[4];
#pragma unroll
        for (int i = 0; i < 4; ++i) pv[i] = pv_ptr[i];

        floatx4 acc[4];
#pragma unroll
        for (int i = 0; i < 4; ++i) acc[i] = (floatx4)0.f;

#pragma unroll
        for (int kt = 0; kt < 12; ++kt) {
            short8 a = *(const short8*)&h_lds[p][lm][kt * 32 + lq * 8];
#pragma unroll
            for (int i = 0; i < 4; ++i) acc[i] = MFMA_BF16(a, breg[i][kt], acc[i]);
        }
#pragma unroll
        for (int kt = 12; kt < 16; ++kt) {
            short8 a = *(const short8*)&h_lds[p][lm][kt * 32 + lq * 8];
#pragma unroll
            for (int i = 0; i < 4; ++i) {
                short8 b = *(const short8*)(Wp + (((size_t)(nt0 + i) * 16 + kt) * 64 + l) * 8);
                acc[i] = MFMA_BF16(a, b, acc[i]);
            }
        }

        // tanh + write h_{t+1} into the other buffer
        unsigned short hv[4][4];
#pragma unroll
        for (int i = 0; i < 4; ++i) {
            int n = (nt0 + i) * 16 + lm;
#pragma unroll
            for (int r = 0; r < 4; ++r) {
                float h = fast_tanh(acc[i][r] + pv[i][r]);
                hv[i][r] = f2bf(h);
                h_lds[p ^ 1][lq * 4 + r][n] = hv[i][r];
            }
        }

        __syncthreads();   // single barrier: orders W(1-p) before next R(1-p),
                           // and this step's R(p) before next step's W(p)

        if (!dofc) {
            // layer-0 output straight from registers (32B-coalesced segments)
#pragma unroll
            for (int i = 0; i < 4; ++i) {
                int n = (nt0 + i) * 16 + lm;
#pragma unroll
                for (int r = 0; r < 4; ++r)
                    out0b[((size_t)t * 64 + b0 + lq * 4 + r) * 512 + n] = hv[i][r];
            }
        }
    }

    if (dofc && tid < 160) {   // FC head: 16 batches x 10 classes (final h in buf 0)
        int b = tid / 10, c = tid % 10;
        float s = bfc[c];
        for (int n = 0; n < 512; ++n) s += bf2f(h_lds[0][b][n]) * wfc[c * 512 + n];
        out[(size_t)(b0 + b) * 10 + c] = s;
    }
}

extern "C" void kernel_launch(void* const* d_in, const int* in_sizes, int n_in,
                              void* d_out, int out_size, void* d_ws, size_t ws_size,
                              hipStream_t stream) {
    const float* x    = (const float*)d_in[0];
    const float* wih0 = (const float*)d_in[1];
    const float* whh0 = (const float*)d_in[2];
    const float* bih0 = (const float*)d_in[3];
    const float* bhh0 = (const float*)d_in[4];
    const float* wih1 = (const float*)d_in[5];
    const float* whh1 = (const float*)d_in[6];
    const float* bih1 = (const float*)d_in[7];
    const float* bhh1 = (const float*)d_in[8];
    const float* wfc  = (const float*)d_in[9];
    const float* bfc  = (const float*)d_in[10];
    float* out = (float*)d_out;

    unsigned short* wsb   = (unsigned short*)d_ws;
    unsigned short* xb    = wsb + OFS_XB;
    unsigned short* out0b = wsb + OFS_OUT0B;
    float* pre = (float*)((char*)d_ws + PRE_B);

    // 1. pack weights (bf16 B-frag order) + convert x to bf16
    prep_kernel<<<dim3(4544), dim3(256), 0, stream>>>(x, whh0, whh1, wih1, wih0, wsb);
    // 2. pre0 = x @ w_ih0^T + b_ih0 + b_hh0  (packed layout)
    proj_kernel<<<dim3(512), dim3(512), 0, stream>>>(xb, wsb + OFS_IH0, bih0, bhh0, pre, 8, 1);
    // 3. layer-0 scan -> out0b (bf16, rows t*64+b)
    recur_kernel<<<dim3(4), dim3(512), 0, stream>>>(pre, wsb + OFS_HH0, out0b,
                                                    nullptr, nullptr, nullptr, 0);
    // 4. pre1 = out0 @ w_ih1^T + b_ih1 + b_hh1  (packed layout)
    proj_kernel<<<dim3(512), dim3(512), 0, stream>>>(out0b, wsb + OFS_IH1, bih1, bhh1, pre, 16, 0);
    // 5. layer-1 scan + FC head -> out
    recur_kernel<<<dim3(4), dim3(512), 0, stream>>>(pre, wsb + OFS_HH1, nullptr,
                                                    wfc, bfc, out, 1);
}

// Round 4
// 3862.005 us; speedup vs baseline: 1.6449x; 1.1861x over previous
//
#include <hip/hip_runtime.h>
#include <hip/hip_bf16.h>
#include <math.h>

// ---------------------------------------------------------------------------
// 2-layer tanh RNN, B=64 S=512 I=256 H=512, fp32 in/out, bf16 MFMA compute.
// Round 4: col-split recurrence (16 blocks = 4 batch-groups x 4 col-slices),
// per-step h-slice exchange via global memory + release/acquire flags.
// DEADLOCK FIX vs R3: flag post (wave 0) and polls (waves 1-3) are in
// different waves, so the post can never be starved by a spinning poll.
//
// ws layout (bytes):
//   [0)        Wp_hh0  bf16 packed  512 KB
//   [512K)     Wp_hh1  bf16 packed  512 KB
//   [1M)       Wp_ih1  bf16 packed  512 KB
//   [1.5M)     Wp_ih0  bf16 packed  256 KB
//   [1835008)  hex1    layer-1 exchange, 2 slots x 4 g x 16 x 512 bf16 = 128 KB
//   [1966080)  flags   flags0[16] + flags1[16] u32 = 128 B
//   [2M)       xb      bf16 [32768][256]    16 MB
//   [18874368) out0b   bf16 [512][64][512]  32 MB  (= layer-0 exchange)
//   [52428800) pre     fp32 PACKED ((t*16+blk)*512+tid)*4+r   64 MB
// ---------------------------------------------------------------------------

typedef __attribute__((ext_vector_type(8))) short  short8;
typedef __attribute__((ext_vector_type(4))) float  floatx4;
typedef __attribute__((ext_vector_type(4))) unsigned int uintx4;

#define MFMA_BF16(a, b, c) __builtin_amdgcn_mfma_f32_16x16x32_bf16((a), (b), (c), 0, 0, 0)

// offsets in u16 units for bf16 regions
#define OFS_HH0   ((size_t)0)
#define OFS_HH1   ((size_t)262144)
#define OFS_IH1   ((size_t)524288)
#define OFS_IH0   ((size_t)786432)
#define OFS_XB    ((size_t)1048576)
#define OFS_OUT0B ((size_t)9437184)
#define HEX1_BYTE  ((size_t)1835008)
#define FLAGS_BYTE ((size_t)1966080)
#define PRE_B      ((size_t)52428800)

__device__ __forceinline__ unsigned short f2bf(float f) {
    unsigned u = __builtin_bit_cast(unsigned, f);
    u += 0x7fffu + ((u >> 16) & 1u);          // round-to-nearest-even
    return (unsigned short)(u >> 16);
}
__device__ __forceinline__ float bf2f(unsigned short h) {
    return __builtin_bit_cast(float, ((unsigned)h) << 16);
}
__device__ __forceinline__ float fast_tanh(float x) {
    float z = fminf(9.0f, fmaxf(-9.0f, x));
    float e = __builtin_amdgcn_exp2f(z * 2.88539008f);   // e^{2z}
    return (e - 1.0f) * __builtin_amdgcn_rcpf(e + 1.0f);
}

// ---- prep: pack weights into MFMA B-fragment order + convert x + flags ----
__device__ __forceinline__ void pack_w(const float* __restrict__ W,
                                       unsigned short* __restrict__ Wp,
                                       int KT, int idx) {
    int l  = idx & 63;
    int kt = (idx >> 6) % KT;
    int nt = (idx >> 6) / KT;
    int Kdim = KT * 32;
    int row = nt * 16 + (l & 15);
    int col = kt * 32 + (l >> 4) * 8;
    const float* s = W + (size_t)row * Kdim + col;
    short8 v;
#pragma unroll
    for (int j = 0; j < 8; ++j) v[j] = (short)f2bf(s[j]);
    *(short8*)(Wp + (size_t)idx * 8) = v;
}

__global__ void prep_kernel(const float* __restrict__ x,
                            const float* __restrict__ whh0,
                            const float* __restrict__ whh1,
                            const float* __restrict__ wih1,
                            const float* __restrict__ wih0,
                            unsigned short* __restrict__ wsb) {
    int blk = blockIdx.x, tid = threadIdx.x;
    if (blk < 128) {
        pack_w(whh0, wsb + OFS_HH0, 16, blk * 256 + tid);
    } else if (blk < 256) {
        pack_w(whh1, wsb + OFS_HH1, 16, (blk - 128) * 256 + tid);
    } else if (blk < 384) {
        pack_w(wih1, wsb + OFS_IH1, 16, (blk - 256) * 256 + tid);
    } else if (blk < 448) {
        pack_w(wih0, wsb + OFS_IH0, 8, (blk - 384) * 256 + tid);
    } else if (blk < 4544) {
        size_t e = ((size_t)(blk - 448) * 256 + tid) * 8;
        const float* s = x + e;
        short8 v;
#pragma unroll
        for (int j = 0; j < 8; ++j) v[j] = (short)f2bf(s[j]);
        *(short8*)(wsb + OFS_XB + e) = v;
    } else {
        if (tid < 32) ((unsigned int*)((char*)wsb + FLAGS_BYTE))[tid] = 0u;
    }
}

// ---- proj: pre = A(bf16) @ W^T + bias1 + bias2 -> fp32, PACKED for recur --
// recur mapping: blk2 = g*4+slice, tid2 = w2*64+lq2*16+lm2, pv[r2].
// element (t,b,n): g=b>>4, br=b&15, slice=n>>7, w2=(n>>4)&7, lm2=n&15,
//   lq2=br>>2, r2=br&3; idx = ((t*16 + g*4+slice)*512 + tid2)*4 + r2
__global__ __launch_bounds__(512) void proj_kernel(
        const unsigned short* __restrict__ A,
        const unsigned short* __restrict__ Wp,
        const float* __restrict__ bias1, const float* __restrict__ bias2,
        float* __restrict__ out, int KT, int remap) {
    int tid = threadIdx.x, blk = blockIdx.x;
    int w = tid >> 6, l = tid & 63, lm = l & 15, lq = l >> 4;
    int mg = w >> 1, nh = w & 1;
    int Kdim = KT * 32;
    int r0 = blk * 64 + mg * 16;

    floatx4 acc[16];
#pragma unroll
    for (int i = 0; i < 16; ++i) acc[i] = (floatx4)0.f;

    for (int kt = 0; kt < KT; ++kt) {
        short8 a = *(const short8*)(A + (size_t)(r0 + lm) * Kdim + kt * 32 + lq * 8);
#pragma unroll
        for (int i = 0; i < 16; ++i) {
            int ntg = nh * 16 + i;
            short8 b = *(const short8*)(Wp + (((size_t)ntg * KT + kt) * 64 + l) * 8);
            acc[i] = MFMA_BF16(a, b, acc[i]);
        }
    }
#pragma unroll
    for (int i = 0; i < 16; ++i) {
        int n = (nh * 16 + i) * 16 + lm;
        float bs = bias1[n] + bias2[n];
        int slice2 = n >> 7, w2 = (n >> 4) & 7, lm2 = n & 15;
#pragma unroll
        for (int r = 0; r < 4; ++r) {
            int row = r0 + lq * 4 + r;
            int tt, b;
            if (remap) { b = row >> 9; tt = row & 511; }
            else       { tt = row >> 6; b = row & 63; }
            int g2 = b >> 4, br = b & 15;
            int tid2 = w2 * 64 + (br >> 2) * 16 + lm2;
            size_t idx = (((size_t)tt * 16 + g2 * 4 + slice2) * 512 + tid2) * 4 + (br & 3);
            out[idx] = acc[i][r] + bs;
        }
    }
}

// ---- recur: 16 blocks = 4 groups x 4 slices, per-step h exchange ---------
// mode 0: layer 0, exchange = out0b (append-only, indexed by t)
// mode 1: layer 1, exchange = hex1 (2 slots), FC head at end (slice 0 only)
__global__ __launch_bounds__(512, 2) void recur_kernel(
        const float* __restrict__ pre,
        const unsigned short* __restrict__ Wp,
        unsigned int* __restrict__ ex,      // u32 col-pairs
        unsigned int* __restrict__ flags,   // [16]
        const float* __restrict__ wfc, const float* __restrict__ bfc,
        float* __restrict__ out, int mode) {
    __shared__ unsigned short w_lds[8 * 4 * 64 * 8];   // 32 KB: [nt_l][kt-12][lane][8]
    __shared__ unsigned short h_lds[2][16][512];       // 32 KB, XOR-swizzled chunks

    const int tid = threadIdx.x;
    const int w = tid >> 6, l = tid & 63, lm = l & 15, lq = l >> 4;
    const int blk = blockIdx.x, g = blk >> 2, slice = blk & 3;
    const int ntg = slice * 8 + w;            // global 16-col tile
    const int ncol = ntg * 16 + lm;           // global col this thread produces

    // zero h buf 0
    {
        uintx4* hz = (uintx4*)&h_lds[0][0][0];
        for (int i = tid; i < 1024; i += 512) hz[i] = (uintx4)0u;
    }
    // stage W k-tiles 12..15 into LDS
    for (int c = tid; c < 2048; c += 512) {
        int nt_l = c >> 8, rem = c & 255, kt = 12 + (rem >> 6), ll = rem & 63;
        ((uintx4*)w_lds)[c] =
            *(const uintx4*)(Wp + (((size_t)(slice * 8 + nt_l) * 16 + kt) * 64 + ll) * 8);
    }
    // register-resident B fragments, k-tiles 0..11 (48 VGPR)
    short8 breg[12];
#pragma unroll
    for (int kt = 0; kt < 12; ++kt)
        breg[kt] = *(const short8*)(Wp + (((size_t)ntg * 16 + kt) * 64 + l) * 8);
    __syncthreads();

    // read-phase constants: thread covers (row rrow, cols cgrp*16..+15)
    const int rrow = tid >> 5;
    const int cgrp = tid & 31;
    const bool do_load = (cgrp >> 3) != slice;     // own slice comes from regs
    const int pc0 = ((cgrp * 2) ^ (rrow & 7));     // phys chunk of cols cgrp*16..+7
    const int pc1 = ((cgrp * 2 + 1) ^ (rrow & 7));
    const int mycp = ncol >> 1;                    // col-pair (even-lm lanes store)
    // poller assignment: lane 0 of waves 1..3 polls partner slice (slice+w)&3
    const bool is_poster = (tid == 0);
    const bool is_poller = (l == 0) && (w >= 1) && (w <= 3);
    const int ps = (slice + w) & 3;                // partner slice for waves 1..3

    const floatx4* pvp = (const floatx4*)(pre + ((size_t)blk * 512 + tid) * 4);

    for (int t = 0; t < 512; ++t) {
        const int p = t & 1;
        floatx4 pv = *pvp;
        pvp += 8192;                                // 16*512 floatx4 per step

        floatx4 acc = (floatx4)0.f;
#pragma unroll
        for (int kt = 0; kt < 12; ++kt) {
            int ch = (kt * 4 + lq) ^ (lm & 7);
            short8 a = *(const short8*)&h_lds[p][lm][ch * 8];
            acc = MFMA_BF16(a, breg[kt], acc);
        }
#pragma unroll
        for (int kt = 12; kt < 16; ++kt) {
            int ch = (kt * 4 + lq) ^ (lm & 7);
            short8 a = *(const short8*)&h_lds[p][lm][ch * 8];
            short8 b = *(const short8*)&w_lds[(((size_t)w * 4 + (kt - 12)) * 64 + l) * 8];
            acc = MFMA_BF16(a, b, acc);
        }

        // tanh -> own-slice LDS write + pack col-pairs for exchange
        unsigned int packv[4];
#pragma unroll
        for (int r = 0; r < 4; ++r) {
            int row = lq * 4 + r;
            float h = fast_tanh(acc[r] + pv[r]);
            unsigned int hb = f2bf(h);
            h_lds[p ^ 1][row][(((ncol >> 3) ^ (row & 7)) << 3) | (ncol & 7)] =
                (unsigned short)hb;
            unsigned int other = (unsigned int)__shfl_xor((int)hb, 1);
            packv[r] = hb | (other << 16);
        }

        unsigned int* exw = (mode == 0)
            ? ex + ((size_t)t * 64 + g * 16) * 256
            : ex + ((size_t)(((t + 1) & 1) * 4 + g) * 16) * 256;

        if (!(lm & 1)) {                      // plain stores; barrier drains vmcnt
#pragma unroll
            for (int r = 0; r < 4; ++r)
                exw[(size_t)(lq * 4 + r) * 256 + mycp] = packv[r];
        }
        __syncthreads();   // all exchange stores drained (vmcnt 0) + LDS writes done

        if (is_poster) {   // wave 0: release-post our step count
            __hip_atomic_fetch_add(&flags[blk], 1u,
                                   __ATOMIC_RELEASE, __HIP_MEMORY_SCOPE_AGENT);
        }
        if (is_poller) {   // waves 1-3: acquire-poll one partner each
            unsigned int tgt = (unsigned int)(t + 1);
            while (__hip_atomic_load(&flags[g * 4 + ps],
                                     __ATOMIC_ACQUIRE, __HIP_MEMORY_SCOPE_AGENT) < tgt)
                __builtin_amdgcn_s_sleep(2);
        }
        __syncthreads();   // partners posted; acquire invalidated L1/L2 CU-wide

        if (do_load) {     // plain vector loads of partner col-pairs
            const uintx4* src = (const uintx4*)(exw + (size_t)rrow * 256 + cgrp * 8);
            uintx4 v0 = src[0];
            uintx4 v1 = src[1];
            *(uintx4*)&h_lds[p ^ 1][rrow][pc0 * 8] = v0;
            *(uintx4*)&h_lds[p ^ 1][rrow][pc1 * 8] = v1;
        }
        __syncthreads();   // h_{t+1} assembled before next step's MFMA
    }

    // FC head: final h_512 lives in buf 0 (512 is even)
    if (mode == 1 && slice == 0 && tid < 160) {
        int b = tid / 10, c = tid % 10;
        float s = bfc[c];
        for (int n = 0; n < 512; ++n) {
            unsigned short hb = h_lds[0][b][(((n >> 3) ^ (b & 7)) << 3) | (n & 7)];
            s += bf2f(hb) * wfc[c * 512 + n];
        }
        out[(size_t)(g * 16 + b) * 10 + c] = s;
    }
}

extern "C" void kernel_launch(void* const* d_in, const int* in_sizes, int n_in,
                              void* d_out, int out_size, void* d_ws, size_t ws_size,
                              hipStream_t stream) {
    const float* x    = (const float*)d_in[0];
    const float* wih0 = (const float*)d_in[1];
    const float* whh0 = (const float*)d_in[2];
    const float* bih0 = (const float*)d_in[3];
    const float* bhh0 = (const float*)d_in[4];
    const float* wih1 = (const float*)d_in[5];
    const float* whh1 = (const float*)d_in[6];
    const float* bih1 = (const float*)d_in[7];
    const float* bhh1 = (const float*)d_in[8];
    const float* wfc  = (const float*)d_in[9];
    const float* bfc  = (const float*)d_in[10];
    float* out = (float*)d_out;

    unsigned short* wsb   = (unsigned short*)d_ws;
    unsigned short* xb    = wsb + OFS_XB;
    unsigned short* out0b = wsb + OFS_OUT0B;
    unsigned int* ex0    = (unsigned int*)(wsb + OFS_OUT0B);
    unsigned int* ex1    = (unsigned int*)((char*)d_ws + HEX1_BYTE);
    unsigned int* flags0 = (unsigned int*)((char*)d_ws + FLAGS_BYTE);
    unsigned int* flags1 = flags0 + 16;
    float* pre = (float*)((char*)d_ws + PRE_B);

    // 1. pack weights + convert x + zero flags
    prep_kernel<<<dim3(4545), dim3(256), 0, stream>>>(x, whh0, whh1, wih1, wih0, wsb);
    // 2. pre0 = x @ w_ih0^T + b_ih0 + b_hh0  (packed for recur)
    proj_kernel<<<dim3(512), dim3(512), 0, stream>>>(xb, wsb + OFS_IH0, bih0, bhh0, pre, 8, 1);
    // 3. layer-0 scan (col-split, exchange via out0b)
    recur_kernel<<<dim3(16), dim3(512), 0, stream>>>(pre, wsb + OFS_HH0, ex0, flags0,
                                                     nullptr, nullptr, nullptr, 0);
    // 4. pre1 = out0 @ w_ih1^T + b_ih1 + b_hh1
    proj_kernel<<<dim3(512), dim3(512), 0, stream>>>(out0b, wsb + OFS_IH1, bih1, bhh1, pre, 16, 0);
    // 5. layer-1 scan + FC head
    recur_kernel<<<dim3(16), dim3(512), 0, stream>>>(pre, wsb + OFS_HH1, ex1, flags1,
                                                     wfc, bfc, out, 1);
}

// Round 5
// 3187.234 us; speedup vs baseline: 1.9932x; 1.2117x over previous
//
#include <hip/hip_runtime.h>
#include <hip/hip_bf16.h>
#include <math.h>

// ---------------------------------------------------------------------------
// 2-layer tanh RNN, B=64 S=512 I=256 H=512, fp32 in/out, bf16 MFMA compute.
// Round 5: BOTH layers fused in one persistent kernel. 16 blocks =
// 4 batch-groups x 4 col-slices. Layer-1 consumes h0 directly from the
// block's own LDS (assembled by layer-0's exchange) via streamed W_ih1
// MFMAs -- no pre1 GEMM, no out0b. Deferred-load exchange: partner slices
// for iteration i were posted at iteration i-1, so polls are hits and the
// L3 load latency hides under the W_ih1 stream phase.
//
// Iteration i (i = 0..513):  L0 at step t=i (i<=511), L1 at step s=i-2 (i>=2)
//   A: poll flags0>=i, flags1>=i-2 (posted one iteration ago); barrier
//   B: issue partner loads: h0_i slices (hex0), h1_{i-3} slices (hex1)
//   C: L1: acc1 = sum_kt W_ih1 . h0_{i-1}   (B-frags streamed from L2)
//   D: commit loaded partner data to LDS (h0 ring slot i%3, h1 slot (i-1)&1);
//      barrier
//   E: L0: acc0 = W_hh0 . h0_i (breg+LDS kt) + pre0; tanh; own slice ->
//      h0 ring slot (i+1)%3 + hex0 slot (i+1)&1
//   F: L1: acc1 += W_hh1 . h1_{i-3}; tanh(acc1+b1); own slice ->
//      h1 slot i&1 + hex1 slot i&1
//   G: barrier; wave0 posts flags0=i+1, wave4 posts flags1=i-1
//
// ws layout (bytes):
//   [0)        Wp_hh0  bf16 packed  512 KB
//   [524288)   Wp_hh1  bf16 packed  512 KB
//   [1048576)  Wp_ih1  bf16 packed  512 KB
//   [1572864)  Wp_ih0  bf16 packed  256 KB
//   [1835008)  hex0    2 slots x 4 g x 16 x 512 bf16 = 128 KB
//   [1966080)  hex1    2 slots x 4 g x 16 x 512 bf16 = 128 KB
//   [2097152)  xb      bf16 [32768][256]  16 MB
//   [18874368) flags   flags0[16] + flags1[16] u32
//   [52428800) pre     fp32 PACKED ((t*16+blk)*512+tid)*4+r   64 MB
// ---------------------------------------------------------------------------

typedef __attribute__((ext_vector_type(8))) short  short8;
typedef __attribute__((ext_vector_type(4))) float  floatx4;
typedef __attribute__((ext_vector_type(4))) unsigned int uintx4;

#define MFMA_BF16(a, b, c) __builtin_amdgcn_mfma_f32_16x16x32_bf16((a), (b), (c), 0, 0, 0)

// offsets in u16 units for bf16 regions
#define OFS_HH0   ((size_t)0)
#define OFS_HH1   ((size_t)262144)
#define OFS_IH1   ((size_t)524288)
#define OFS_IH0   ((size_t)786432)
#define OFS_XB    ((size_t)1048576)
#define HEX0_BYTE  ((size_t)1835008)
#define HEX1_BYTE  ((size_t)1966080)
#define FLAGS_BYTE ((size_t)18874368)
#define PRE_B      ((size_t)52428800)

__device__ __forceinline__ unsigned short f2bf(float f) {
    unsigned u = __builtin_bit_cast(unsigned, f);
    u += 0x7fffu + ((u >> 16) & 1u);          // round-to-nearest-even
    return (unsigned short)(u >> 16);
}
__device__ __forceinline__ float bf2f(unsigned short h) {
    return __builtin_bit_cast(float, ((unsigned)h) << 16);
}
__device__ __forceinline__ float fast_tanh(float x) {
    float z = fminf(9.0f, fmaxf(-9.0f, x));
    float e = __builtin_amdgcn_exp2f(z * 2.88539008f);   // e^{2z}
    return (e - 1.0f) * __builtin_amdgcn_rcpf(e + 1.0f);
}

// ---- prep: pack weights into MFMA B-fragment order + convert x + flags ----
__device__ __forceinline__ void pack_w(const float* __restrict__ W,
                                       unsigned short* __restrict__ Wp,
                                       int KT, int idx) {
    int l  = idx & 63;
    int kt = (idx >> 6) % KT;
    int nt = (idx >> 6) / KT;
    int Kdim = KT * 32;
    int row = nt * 16 + (l & 15);
    int col = kt * 32 + (l >> 4) * 8;
    const float* s = W + (size_t)row * Kdim + col;
    short8 v;
#pragma unroll
    for (int j = 0; j < 8; ++j) v[j] = (short)f2bf(s[j]);
    *(short8*)(Wp + (size_t)idx * 8) = v;
}

__global__ void prep_kernel(const float* __restrict__ x,
                            const float* __restrict__ whh0,
                            const float* __restrict__ whh1,
                            const float* __restrict__ wih1,
                            const float* __restrict__ wih0,
                            unsigned short* __restrict__ wsb) {
    int blk = blockIdx.x, tid = threadIdx.x;
    if (blk < 128) {
        pack_w(whh0, wsb + OFS_HH0, 16, blk * 256 + tid);
    } else if (blk < 256) {
        pack_w(whh1, wsb + OFS_HH1, 16, (blk - 128) * 256 + tid);
    } else if (blk < 384) {
        pack_w(wih1, wsb + OFS_IH1, 16, (blk - 256) * 256 + tid);
    } else if (blk < 448) {
        pack_w(wih0, wsb + OFS_IH0, 8, (blk - 384) * 256 + tid);
    } else if (blk < 4544) {
        size_t e = ((size_t)(blk - 448) * 256 + tid) * 8;
        const float* s = x + e;
        short8 v;
#pragma unroll
        for (int j = 0; j < 8; ++j) v[j] = (short)f2bf(s[j]);
        *(short8*)(wsb + OFS_XB + e) = v;
    } else {
        if (tid < 32) ((unsigned int*)((char*)wsb + FLAGS_BYTE))[tid] = 0u;
    }
}

// ---- proj: pre0 = xb @ W_ih0^T + b_ih0 + b_hh0 -> fp32, PACKED for fused --
__global__ __launch_bounds__(512) void proj_kernel(
        const unsigned short* __restrict__ A,
        const unsigned short* __restrict__ Wp,
        const float* __restrict__ bias1, const float* __restrict__ bias2,
        float* __restrict__ out, int KT, int remap) {
    int tid = threadIdx.x, blk = blockIdx.x;
    int w = tid >> 6, l = tid & 63, lm = l & 15, lq = l >> 4;
    int mg = w >> 1, nh = w & 1;
    int Kdim = KT * 32;
    int r0 = blk * 64 + mg * 16;

    floatx4 acc[16];
#pragma unroll
    for (int i = 0; i < 16; ++i) acc[i] = (floatx4)0.f;

    for (int kt = 0; kt < KT; ++kt) {
        short8 a = *(const short8*)(A + (size_t)(r0 + lm) * Kdim + kt * 32 + lq * 8);
#pragma unroll
        for (int i = 0; i < 16; ++i) {
            int ntg = nh * 16 + i;
            short8 b = *(const short8*)(Wp + (((size_t)ntg * KT + kt) * 64 + l) * 8);
            acc[i] = MFMA_BF16(a, b, acc[i]);
        }
    }
#pragma unroll
    for (int i = 0; i < 16; ++i) {
        int n = (nh * 16 + i) * 16 + lm;
        float bs = bias1[n] + bias2[n];
        int slice2 = n >> 7, w2 = (n >> 4) & 7, lm2 = n & 15;
#pragma unroll
        for (int r = 0; r < 4; ++r) {
            int row = r0 + lq * 4 + r;
            int tt, b;
            if (remap) { b = row >> 9; tt = row & 511; }
            else       { tt = row >> 6; b = row & 63; }
            int g2 = b >> 4, br = b & 15;
            int tid2 = w2 * 64 + (br >> 2) * 16 + lm2;
            size_t idx = (((size_t)tt * 16 + g2 * 4 + slice2) * 512 + tid2) * 4 + (br & 3);
            out[idx] = acc[i][r] + bs;
        }
    }
}

// ---- fused 2-layer scan: 16 blocks = 4 groups x 4 slices -----------------
__global__ __launch_bounds__(512, 2) void fused_kernel(
        const float* __restrict__ pre,           // packed fp32 (layer-0 input proj)
        const unsigned short* __restrict__ Whh0, // packed bf16 KT=16
        const unsigned short* __restrict__ Whh1,
        const unsigned short* __restrict__ Wih1,
        unsigned int* __restrict__ hex0,         // u32 col-pairs, 2 slots
        unsigned int* __restrict__ hex1,
        unsigned int* __restrict__ flags0,       // [16]
        unsigned int* __restrict__ flags1,       // [16]
        const float* __restrict__ bih1, const float* __restrict__ bhh1,
        const float* __restrict__ wfc, const float* __restrict__ bfc,
        float* __restrict__ out) {
    __shared__ unsigned short w_lds0[16384];        // 32 KB: hh0 kt 12..15
    __shared__ unsigned short w_lds1[16384];        // 32 KB: hh1 kt 12..15
    __shared__ unsigned short h0[3][16][512];       // 48 KB ring
    __shared__ unsigned short h1[2][16][512];       // 32 KB dbuf

    const int tid = threadIdx.x;
    const int w = tid >> 6, l = tid & 63, lm = l & 15, lq = l >> 4;
    const int blk = blockIdx.x, g = blk >> 2, slice = blk & 3;
    const int ntg = slice * 8 + w;            // global 16-col tile
    const int ncol = ntg * 16 + lm;           // global col this thread produces

    // zero h0 slot 0 and h1 slot 1 (the t<0 states)
    {
        uintx4* z0 = (uintx4*)&h0[0][0][0];
        uintx4* z1 = (uintx4*)&h1[1][0][0];
        for (int i = tid; i < 512; i += 512) { z0[i] = (uintx4)0u; z1[i] = (uintx4)0u; }
    }
    // stage W_hh kt 12..15 into LDS (both layers)
    for (int c = tid; c < 2048; c += 512) {
        int nt_l = c >> 8, rem = c & 255, kt = 12 + (rem >> 6), ll = rem & 63;
        size_t src = (((size_t)(slice * 8 + nt_l) * 16 + kt) * 64 + ll) * 8;
        ((uintx4*)w_lds0)[c] = *(const uintx4*)(Whh0 + src);
        ((uintx4*)w_lds1)[c] = *(const uintx4*)(Whh1 + src);
    }
    // register-resident W_hh fragments, kt 0..11, both layers (96 VGPR)
    short8 breg0[12], breg1[12];
#pragma unroll
    for (int kt = 0; kt < 12; ++kt) {
        size_t src = (((size_t)ntg * 16 + kt) * 64 + l) * 8;
        breg0[kt] = *(const short8*)(Whh0 + src);
        breg1[kt] = *(const short8*)(Whh1 + src);
    }
    const float b1v = bih1[ncol] + bhh1[ncol];
    __syncthreads();

    // exchange-phase constants (R4-proven)
    const int rrow = tid >> 5;
    const int cgrp = tid & 31;
    const bool dl = (cgrp >> 3) != slice;          // partner columns only
    const int pc0 = ((cgrp * 2) ^ (rrow & 7));
    const int pc1 = ((cgrp * 2 + 1) ^ (rrow & 7));
    const int mycp = ncol >> 1;
    const bool pl0 = (l == 0) && (w >= 1) && (w <= 3);
    const bool pl1 = (l == 0) && (w >= 5) && (w <= 7);
    const int ps0 = (slice + w) & 3;
    const int ps1 = (slice + w - 4) & 3;

    const floatx4* pvp = (const floatx4*)(pre + ((size_t)blk * 512 + tid) * 4);

    int slotC = 2, slotE = 0, slotW = 1;

    for (int i = 0; i <= 513; ++i) {
        // --- A: polls (targets posted one iteration ago) ---
        if (pl0 && i >= 1 && i <= 512) {
            unsigned int tgt = (unsigned int)i;
            while (__hip_atomic_load(&flags0[g * 4 + ps0],
                                     __ATOMIC_ACQUIRE, __HIP_MEMORY_SCOPE_AGENT) < tgt)
                __builtin_amdgcn_s_sleep(2);
        }
        if (pl1 && i >= 3) {
            unsigned int tgt = (unsigned int)(i - 2);
            while (__hip_atomic_load(&flags1[g * 4 + ps1],
                                     __ATOMIC_ACQUIRE, __HIP_MEMORY_SCOPE_AGENT) < tgt)
                __builtin_amdgcn_s_sleep(2);
        }
        __syncthreads();

        // --- B: issue partner loads (latency hides under C) ---
        const bool ld0 = dl && (i >= 1) && (i <= 512);
        const bool ld1 = dl && (i >= 3);
        uintx4 v0a, v0b, v1a, v1b;
        if (ld0) {
            const uintx4* s = (const uintx4*)(hex0 + (size_t)((i & 1) * 4 + g) * 4096
                                              + rrow * 256 + cgrp * 8);
            v0a = s[0]; v0b = s[1];
        }
        if (ld1) {
            const uintx4* s = (const uintx4*)(hex1 + (size_t)(((i - 1) & 1) * 4 + g) * 4096
                                              + rrow * 256 + cgrp * 8);
            v1a = s[0]; v1b = s[1];
        }

        // --- C: L1 input projection, W_ih1 streamed from L2 ---
        floatx4 acc1 = (floatx4)0.f;
        if (i >= 2) {
#pragma unroll
            for (int kt = 0; kt < 16; ++kt) {
                int ch = (kt * 4 + lq) ^ (lm & 7);
                short8 a = *(const short8*)&h0[slotC][lm][ch * 8];
                short8 b = *(const short8*)(Wih1 + (((size_t)ntg * 16 + kt) * 64 + l) * 8);
                acc1 = MFMA_BF16(a, b, acc1);
            }
        }

        // --- D: commit partner data to LDS ---
        if (ld0) {
            *(uintx4*)&h0[slotE][rrow][pc0 * 8] = v0a;
            *(uintx4*)&h0[slotE][rrow][pc1 * 8] = v0b;
        }
        if (ld1) {
            *(uintx4*)&h1[(i - 1) & 1][rrow][pc0 * 8] = v1a;
            *(uintx4*)&h1[(i - 1) & 1][rrow][pc1 * 8] = v1b;
        }
        __syncthreads();

        // --- E: layer 0 step i ---
        if (i <= 511) {
            floatx4 pv = *pvp;
            floatx4 acc0 = (floatx4)0.f;
#pragma unroll
            for (int kt = 0; kt < 12; ++kt) {
                int ch = (kt * 4 + lq) ^ (lm & 7);
                short8 a = *(const short8*)&h0[slotE][lm][ch * 8];
                acc0 = MFMA_BF16(a, breg0[kt], acc0);
            }
#pragma unroll
            for (int kt = 12; kt < 16; ++kt) {
                int ch = (kt * 4 + lq) ^ (lm & 7);
                short8 a = *(const short8*)&h0[slotE][lm][ch * 8];
                short8 b = *(const short8*)&w_lds0[(((size_t)w * 4 + (kt - 12)) * 64 + l) * 8];
                acc0 = MFMA_BF16(a, b, acc0);
            }
            unsigned int packv[4];
#pragma unroll
            for (int r = 0; r < 4; ++r) {
                int row = lq * 4 + r;
                float h = fast_tanh(acc0[r] + pv[r]);
                unsigned int hb = f2bf(h);
                h0[slotW][row][(((ncol >> 3) ^ (row & 7)) << 3) | (ncol & 7)] =
                    (unsigned short)hb;
                unsigned int other = (unsigned int)__shfl_xor((int)hb, 1);
                packv[r] = hb | (other << 16);
            }
            unsigned int* exw = hex0 + (size_t)(((i + 1) & 1) * 4 + g) * 4096;
            if (!(lm & 1)) {
#pragma unroll
                for (int r = 0; r < 4; ++r)
                    exw[(size_t)(lq * 4 + r) * 256 + mycp] = packv[r];
            }
        }
        pvp += 8192;

        // --- F: layer 1 step i-2 ---
        if (i >= 2) {
#pragma unroll
            for (int kt = 0; kt < 12; ++kt) {
                int ch = (kt * 4 + lq) ^ (lm & 7);
                short8 a = *(const short8*)&h1[(i - 1) & 1][lm][ch * 8];
                acc1 = MFMA_BF16(a, breg1[kt], acc1);
            }
#pragma unroll
            for (int kt = 12; kt < 16; ++kt) {
                int ch = (kt * 4 + lq) ^ (lm & 7);
                short8 a = *(const short8*)&h1[(i - 1) & 1][lm][ch * 8];
                short8 b = *(const short8*)&w_lds1[(((size_t)w * 4 + (kt - 12)) * 64 + l) * 8];
                acc1 = MFMA_BF16(a, b, acc1);
            }
            unsigned int packv[4];
#pragma unroll
            for (int r = 0; r < 4; ++r) {
                int row = lq * 4 + r;
                float h = fast_tanh(acc1[r] + b1v);
                unsigned int hb = f2bf(h);
                h1[i & 1][row][(((ncol >> 3) ^ (row & 7)) << 3) | (ncol & 7)] =
                    (unsigned short)hb;
                unsigned int other = (unsigned int)__shfl_xor((int)hb, 1);
                packv[r] = hb | (other << 16);
            }
            unsigned int* exw = hex1 + (size_t)((i & 1) * 4 + g) * 4096;
            if (!(lm & 1)) {
#pragma unroll
                for (int r = 0; r < 4; ++r)
                    exw[(size_t)(lq * 4 + r) * 256 + mycp] = packv[r];
            }
        }

        __syncthreads();   // drains vmcnt before release posts

        // --- G: posts ---
        if (l == 0 && w == 0 && i <= 511)
            __hip_atomic_fetch_add(&flags0[blk], 1u,
                                   __ATOMIC_RELEASE, __HIP_MEMORY_SCOPE_AGENT);
        if (l == 0 && w == 4 && i >= 2)
            __hip_atomic_fetch_add(&flags1[blk], 1u,
                                   __ATOMIC_RELEASE, __HIP_MEMORY_SCOPE_AGENT);

        slotC = slotE; slotE = slotW; slotW = (slotW + 1 == 3) ? 0 : slotW + 1;
    }

    // --- FC head: slice-0 blocks gather full h1_511 and reduce ---
    if (slice == 0) {
        if (pl1) {   // waves 5..7 lane 0 poll partners for final post (=512)
            while (__hip_atomic_load(&flags1[g * 4 + ps1],
                                     __ATOMIC_ACQUIRE, __HIP_MEMORY_SCOPE_AGENT) < 512u)
                __builtin_amdgcn_s_sleep(2);
        }
        __syncthreads();
        if (dl) {    // load partner h1_511 cols (hex1 slot 513&1 = 1) into h1[1]
            const uintx4* s = (const uintx4*)(hex1 + (size_t)(1 * 4 + g) * 4096
                                              + rrow * 256 + cgrp * 8);
            uintx4 a = s[0], b = s[1];
            *(uintx4*)&h1[1][rrow][pc0 * 8] = a;
            *(uintx4*)&h1[1][rrow][pc1 * 8] = b;
        }
        __syncthreads();
        if (tid < 160) {
            int b = tid / 10, c = tid % 10;
            float s = bfc[c];
            for (int n = 0; n < 512; ++n) {
                unsigned short hb = h1[1][b][(((n >> 3) ^ (b & 7)) << 3) | (n & 7)];
                s += bf2f(hb) * wfc[c * 512 + n];
            }
            out[(size_t)(g * 16 + b) * 10 + c] = s;
        }
    }
}

extern "C" void kernel_launch(void* const* d_in, const int* in_sizes, int n_in,
                              void* d_out, int out_size, void* d_ws, size_t ws_size,
                              hipStream_t stream) {
    const float* x    = (const float*)d_in[0];
    const float* wih0 = (const float*)d_in[1];
    const float* whh0 = (const float*)d_in[2];
    const float* bih0 = (const float*)d_in[3];
    const float* bhh0 = (const float*)d_in[4];
    const float* wih1 = (const float*)d_in[5];
    const float* whh1 = (const float*)d_in[6];
    const float* bih1 = (const float*)d_in[7];
    const float* bhh1 = (const float*)d_in[8];
    const float* wfc  = (const float*)d_in[9];
    const float* bfc  = (const float*)d_in[10];
    float* out = (float*)d_out;

    unsigned short* wsb  = (unsigned short*)d_ws;
    unsigned short* xb   = wsb + OFS_XB;
    unsigned int* hex0   = (unsigned int*)((char*)d_ws + HEX0_BYTE);
    unsigned int* hex1   = (unsigned int*)((char*)d_ws + HEX1_BYTE);
    unsigned int* flags0 = (unsigned int*)((char*)d_ws + FLAGS_BYTE);
    unsigned int* flags1 = flags0 + 16;
    float* pre = (float*)((char*)d_ws + PRE_B);

    // 1. pack weights + convert x + zero flags
    prep_kernel<<<dim3(4545), dim3(256), 0, stream>>>(x, whh0, whh1, wih1, wih0, wsb);
    // 2. pre0 = x @ w_ih0^T + b_ih0 + b_hh0  (packed for fused kernel)
    proj_kernel<<<dim3(512), dim3(512), 0, stream>>>(xb, wsb + OFS_IH0, bih0, bhh0, pre, 8, 1);
    // 3. fused 2-layer scan + FC head
    fused_kernel<<<dim3(16), dim3(512), 0, stream>>>(
        pre, wsb + OFS_HH0, wsb + OFS_HH1, wsb + OFS_IH1,
        hex0, hex1, flags0, flags1, bih1, bhh1, wfc, bfc, out);
}